// Round 5
// baseline (257.208 us; speedup 1.0000x reference)
//
#include <hip/hip_runtime.h>

// Single-pass block-resident cumulative max along H for x:(32,1,1024,1024) fp32.
// Round-4 post-mortem: 3-pass kernels summed ~99us vs 42us single-pass floor
// (x read twice + ws traffic + 3 dispatch tails). New structure: block owns a
// (b, 32-w strip) x H=1024 column strip, scanned through LDS in 8 chunks of
// 128 rows with double-buffered register prefetch. Carry chains in registers.
// HBM traffic = 128 MiB read + 128 MiB write (floor). 36 KB LDS -> 4 blk/CU.

constexpr int B = 32;
constexpr int H = 1024;
constexpr int W = 1024;
constexpr int ROW4 = W / 4;          // 256 float4 per row
constexpr int SW4 = 8;               // strip width: 8 float4 = 32 floats = 128 B
constexpr int NSTRIP = ROW4 / SW4;   // 32 strips per b
constexpr int CH = 128;              // rows per chunk
constexpr int NCHUNK = H / CH;       // 8
constexpr int NT = 256;              // threads per block
constexpr int SEG = 32;              // segments per chunk
constexpr int RPS = CH / SEG;        // 4 rows per segment
constexpr int LPT = CH * SW4 / NT;   // 4 float4 loads/thread/chunk

typedef float floatx4 __attribute__((ext_vector_type(4)));

__device__ __forceinline__ float4 max4(float4 a, float4 b) {
    return make_float4(fmaxf(a.x, b.x), fmaxf(a.y, b.y),
                       fmaxf(a.z, b.z), fmaxf(a.w, b.w));
}

__global__ __launch_bounds__(256) void cummax_onepass(const float* __restrict__ xf,
                                                      float* __restrict__ of) {
    __shared__ float4 buf[2][CH * SW4];   // 2 x 16 KB
    __shared__ float4 smax[SEG][SW4];     // 4 KB

    const int tid = threadIdx.x;
    const int b = blockIdx.x >> 5;        // blockIdx / NSTRIP
    const int strip = blockIdx.x & (NSTRIP - 1);
    const float4* x4 = (const float4*)xf;
    float* out_f = of;
    const size_t base4 = (size_t)b * (H * ROW4) + (size_t)strip * SW4;

    const int s = tid >> 3;               // segment 0..31
    const int wg = tid & 7;               // float4-column within strip

    const float ninf = -__builtin_inff();
    float4 carry = make_float4(ninf, ninf, ninf, ninf);  // same value per wg

    float4 ld[LPT];

    // stage chunk 0
#pragma unroll
    for (int i = 0; i < LPT; ++i) {
        const int e = i * NT + tid;       // element within chunk
        const int hl = e >> 3, w = e & 7;
        ld[i] = x4[base4 + (size_t)hl * ROW4 + w];
    }
#pragma unroll
    for (int i = 0; i < LPT; ++i) buf[0][i * NT + tid] = ld[i];
    __syncthreads();

    for (int c = 0; c < NCHUNK; ++c) {
        const int cb = c & 1, nb = cb ^ 1;

        // prefetch chunk c+1 into registers (in flight across compute)
        if (c + 1 < NCHUNK) {
#pragma unroll
            for (int i = 0; i < LPT; ++i) {
                const int e = i * NT + tid;
                const int hl = e >> 3, w = e & 7;
                ld[i] = x4[base4 + (size_t)((c + 1) * CH + hl) * ROW4 + w];
            }
        }

        // segment max over this thread's RPS rows
        float4 m = buf[cb][(s * RPS) * SW4 + wg];
#pragma unroll
        for (int r = 1; r < RPS; ++r) m = max4(m, buf[cb][(s * RPS + r) * SW4 + wg]);
        smax[s][wg] = m;
        __syncthreads();

        // exclusive prefix over segments < s, plus full-chunk total for carry
        float4 pre = carry, tot = carry;
#pragma unroll
        for (int s2 = 0; s2 < SEG; ++s2) {
            const float4 v = smax[s2][wg];
            if (s2 < s) pre = max4(pre, v);
            tot = max4(tot, v);
        }
        carry = tot;

        // apply + store (running max through this thread's rows)
        float4 a = pre;
#pragma unroll
        for (int r = 0; r < RPS; ++r) {
            a = max4(a, buf[cb][(s * RPS + r) * SW4 + wg]);
            const size_t o = base4 + (size_t)(c * CH + s * RPS + r) * ROW4 + wg;
            floatx4 av = {a.x, a.y, a.z, a.w};
            __builtin_nontemporal_store(av, (floatx4*)out_f + o);
        }

        // stage prefetched chunk into the other buffer
        if (c + 1 < NCHUNK) {
#pragma unroll
            for (int i = 0; i < LPT; ++i) buf[nb][i * NT + tid] = ld[i];
        }
        __syncthreads();
    }
}

extern "C" void kernel_launch(void* const* d_in, const int* in_sizes, int n_in,
                              void* d_out, int out_size, void* d_ws, size_t ws_size,
                              hipStream_t stream) {
    const float* x = (const float*)d_in[0];
    float* out = (float*)d_out;
    cummax_onepass<<<B * NSTRIP, NT, 0, stream>>>(x, out);
}

// Round 6
// 240.567 us; speedup vs baseline: 1.0692x; 1.0692x over previous
//
#include <hip/hip_runtime.h>

// Single-pass cumulative max along H for x:(32,1,1024,1024) fp32 — registers
// only, no LDS data staging.
// Round-5 post-mortem: LDS round-trip cost 8-way bank conflicts on every data
// read (SQ_LDS_BANK_CONFLICT pegged at 2^20) + 32 ds_read_b128/thread for the
// prefix -> 2.67 TB/s. Fix: thread (w=tid&7, hseg=tid>>3) loads its own R=4
// rows straight to registers (each wave load = 8 rows x 128 B full lines);
// per-chunk prefix over 32 h-segments = 3-step __shfl_up scan within wave
// (segments stride 8 lanes) + 512 B LDS exchange of 4 wave totals
// (conflict-free, parity buffers -> 1 barrier/chunk). Plain stores (round-5's
// nontemporal stores showed 1.53x WRITE inflation). Register double-buffer
// prefetches chunk c+1 during chunk c's compute.

constexpr int B = 32;
constexpr int H = 1024;
constexpr int W = 1024;
constexpr int ROW4 = W / 4;          // 256 float4 per row
constexpr int SW4 = 8;               // strip width: 8 float4 = 32 floats = 128 B
constexpr int NSTRIP = ROW4 / SW4;   // 32 strips per b -> 1024 blocks
constexpr int CH = 128;              // rows per chunk (32 hsegs x R)
constexpr int NCHUNK = H / CH;       // 8
constexpr int R = 4;                 // rows per thread per chunk

__device__ __forceinline__ float4 max4(float4 a, float4 b) {
    return make_float4(fmaxf(a.x, b.x), fmaxf(a.y, b.y),
                       fmaxf(a.z, b.z), fmaxf(a.w, b.w));
}

__device__ __forceinline__ float4 shflup4(float4 v, int d) {
    float4 r;
    r.x = __shfl_up(v.x, d, 64);
    r.y = __shfl_up(v.y, d, 64);
    r.z = __shfl_up(v.z, d, 64);
    r.w = __shfl_up(v.w, d, 64);
    return r;
}

__global__ __launch_bounds__(256) void cummax_sp(const float* __restrict__ xf,
                                                 float* __restrict__ of) {
    __shared__ float4 wavetot[2][32];  // [parity][wave*8 + w], 1 KB

    const int tid = threadIdx.x;
    const int lane = tid & 63;
    const int wid = tid >> 6;          // wave 0..3
    const int w = tid & 7;             // float4-col within strip
    const int hsegG = tid >> 3;        // 0..31 (global h-segment in chunk)
    const int hseg_l = (tid >> 3) & 7; // h-segment within wave

    const int b = blockIdx.x >> 5;
    const int strip = blockIdx.x & (NSTRIP - 1);
    const float4* x4 = (const float4*)xf;
    float4* o4 = (float4*)of;
    // thread's base: its column + its first row of chunk 0
    const size_t tbase = (size_t)b * (H * ROW4) + (size_t)strip * SW4 + w;

    const float ninf = -__builtin_inff();
    const float4 ninf4 = make_float4(ninf, ninf, ninf, ninf);
    float4 carry = ninf4;

    float4 cur[R], nxt[R];

#pragma unroll
    for (int r = 0; r < R; ++r)
        cur[r] = x4[tbase + (size_t)(hsegG * R + r) * ROW4];

#pragma unroll
    for (int c = 0; c < NCHUNK; ++c) {
        // prefetch chunk c+1 (independent of everything below)
        if (c + 1 < NCHUNK) {
#pragma unroll
            for (int r = 0; r < R; ++r)
                nxt[r] = x4[tbase + (size_t)((c + 1) * CH + hsegG * R + r) * ROW4];
        }

        // segment max over this thread's R rows
        float4 m = max4(max4(cur[0], cur[1]), max4(cur[2], cur[3]));

        // inclusive shuffle scan over the 8 h-segments of this wave (stride 8)
        float4 incl = m;
        { float4 t = shflup4(incl, 8);  if (lane >= 8)  incl = max4(incl, t); }
        { float4 t = shflup4(incl, 16); if (lane >= 16) incl = max4(incl, t); }
        { float4 t = shflup4(incl, 32); if (lane >= 32) incl = max4(incl, t); }
        float4 ew = shflup4(incl, 8);
        float4 excl = (hseg_l == 0) ? ninf4 : ew;  // exclusive within-wave prefix

        // wave total (lane 56..63 hold it) -> tiny LDS exchange
        if (hseg_l == 7) wavetot[c & 1][wid * 8 + w] = incl;
        __syncthreads();

        float4 crosspre = carry;   // carry folds in here
        float4 tot = carry;
#pragma unroll
        for (int w2 = 0; w2 < 4; ++w2) {
            float4 v = wavetot[c & 1][w2 * 8 + w];
            if (w2 < wid) crosspre = max4(crosspre, v);
            tot = max4(tot, v);
        }
        carry = tot;

        // apply + store
        float4 a = max4(crosspre, excl);
#pragma unroll
        for (int r = 0; r < R; ++r) {
            a = max4(a, cur[r]);
            o4[tbase + (size_t)(c * CH + hsegG * R + r) * ROW4] = a;
        }

        if (c + 1 < NCHUNK) {
#pragma unroll
            for (int r = 0; r < R; ++r) cur[r] = nxt[r];
        }
    }
}

extern "C" void kernel_launch(void* const* d_in, const int* in_sizes, int n_in,
                              void* d_out, int out_size, void* d_ws, size_t ws_size,
                              hipStream_t stream) {
    const float* x = (const float*)d_in[0];
    float* out = (float*)d_out;
    cummax_sp<<<B * NSTRIP, 256, 0, stream>>>(x, out);
}